// Round 3
// baseline (3190.730 us; speedup 1.0000x reference)
//
#include <hip/hip_runtime.h>
#include <math.h>

#define T_ 60
#define N_ 16384
#define C_ 5
#define H_ 20
#define G_ 80
#define HC_ 15
#define N0_ 3190
#define E0_ 31900
#define K_ 5

// workspace layout (float offsets)
#define OFF_SEQ   0
#define OFF_XH    (T_*N_*H_)            // 19,660,800
#define OFF_XHN   (OFF_XH + N_*H_)
#define OFF_NX0   (OFF_XHN + N_)
#define OFF_RX0   (OFF_NX0 + N0_)
#define OFF_TOP5  (OFF_RX0 + N0_)       // int[ N_*K_ ]
#define OFF_SUM1  (OFF_TOP5 + N_*K_)
#define OFF_CNT1  (OFF_SUM1 + N0_*H_)
#define OFF_OBASE (OFF_CNT1 + N0_)

__device__ __forceinline__ float sigf(float x) {
  return __fdividef(1.0f, 1.0f + __expf(-x));
}
__device__ __forceinline__ float tanhf_fast(float x) {
  float xc = fminf(fmaxf(x, -44.0f), 44.0f);
  float e = __expf(2.0f * xc);
  return __fdividef(e - 1.0f, e + 1.0f);
}

// ============================================================================
// Barrier-free role-split LSTM, 2 layers per kernel (4-layer fusion spilled:
// VGPR=256 + 1.47 GB scratch fetch in round 2).
// lane = 4*slot + role; 16 elements/wave. role r owns units 5r..5r+4.
// h exchanged via __shfl_xor(1,2,3); h kept in part order:
// h[5d+u] = h_natural[5*(r^d)+u]. Weight columns pre-permuted per role at
// LDS-stage time (first local layer's Wih stays natural: its input arrives
// in natural order from embed or from seq). Block stride 808 floats puts
// role r at bank 8r -> conflict-free broadcast ds_read_b128.
// ============================================================================

#define WSTRIDE 808
#define BSTRIDE 24

__device__ __forceinline__ void lstm_layer_step(
    const float* __restrict__ wts, const float* __restrict__ biasl,
    int base, int bbase, const float (&in)[20], float (&H)[20], float (&C)[5]) {
  float acc[20];
#pragma unroll
  for (int lr = 0; lr < 20; lr++) {
    float a = biasl[bbase + lr];
    const float* wr = &wts[base + lr * 40];
#pragma unroll
    for (int k = 0; k < 20; k++) a += in[k] * wr[k];
#pragma unroll
    for (int k = 0; k < 20; k++) a += H[k] * wr[20 + k];
    acc[lr] = a;
  }
  float hn[5];
#pragma unroll
  for (int u = 0; u < 5; u++) {
    float si = sigf(acc[u]);
    float sf = sigf(acc[5 + u]);
    float tg = tanhf_fast(acc[10 + u]);
    float so = sigf(acc[15 + u]);
    float cu = sf * C[u] + si * tg;
    C[u] = cu;
    hn[u] = so * tanhf_fast(cu);
  }
#pragma unroll
  for (int u = 0; u < 5; u++) {
    float a1 = __shfl_xor(hn[u], 1, 64);
    float a2 = __shfl_xor(hn[u], 2, 64);
    float a3 = __shfl_xor(hn[u], 3, 64);
    H[u] = hn[u]; H[5 + u] = a1; H[10 + u] = a2; H[15 + u] = a3;
  }
}

// FIRST: input = embed(relu(x @ emb_w)); else input = seq (natural order).
// Wih/bih/bhh pointers are pre-offset to the kernel's first layer.
template <bool FIRST>
__global__ void __launch_bounds__(256, 1) lstm2_kernel(
    const float* __restrict__ xg,      // [T, N, 5] raw codes (FIRST only)
    const float* __restrict__ embw,    // [5, 20]              (FIRST only)
    const float* __restrict__ Wih,     // [2, 80, 20]
    const float* __restrict__ Whh,     // [2, 80, 20]
    const float* __restrict__ bih,     // [2, 80]
    const float* __restrict__ bhh,     // [2, 80]
    float* __restrict__ seq) {         // in (!FIRST) and out: [T, N, 20]
  __shared__ __align__(16) float wts[8 * WSTRIDE];
  __shared__ float biasl[8 * BSTRIDE];
  __shared__ float embl[100];
  const int tid = threadIdx.x;

  // ---- stage weights (role-permuted columns; local-layer-0 Wih natural) ----
  for (int idx = tid; idx < 8 * 820; idx += 256) {
    int blk = idx / 820;            // l_local*4 + r
    int e = idx % 820;
    int l = blk >> 2, r = blk & 3;
    if (e < 800) {
      int lr = e / 40, col = e % 40;
      int g = lr / 5, u = lr % 5;
      int grow = g * 20 + 5 * r + u;
      float v;
      if (col < 20) {
        int k = col;
        int kk = (l == 0) ? k : (5 * (r ^ (k / 5)) + (k % 5));
        v = Wih[l * 1600 + grow * 20 + kk];
      } else {
        int k = col - 20;
        int kk = 5 * (r ^ (k / 5)) + (k % 5);
        v = Whh[l * 1600 + grow * 20 + kk];
      }
      wts[blk * WSTRIDE + lr * 40 + col] = v;
    } else {
      int lr = e - 800;
      int g = lr / 5, u = lr % 5;
      int grow = g * 20 + 5 * r + u;
      biasl[blk * BSTRIDE + lr] = bih[l * 80 + grow] + bhh[l * 80 + grow];
    }
  }
  if (FIRST && tid < 100) embl[tid] = embw[tid];
  __syncthreads();

  const int lane = tid & 63;
  const int wv = tid >> 6;
  const int slot = lane >> 2;
  const int r = lane & 3;
  const int n = (blockIdx.x << 6) + (wv << 4) + slot;

  const int baseA = (0 * 4 + r) * WSTRIDE, bbA = (0 * 4 + r) * BSTRIDE;
  const int baseB = (1 * 4 + r) * WSTRIDE, bbB = (1 * 4 + r) * BSTRIDE;

  float hA[20], hB[20], cA[5], cB[5];
#pragma unroll
  for (int k = 0; k < 20; k++) { hA[k] = 0.f; hB[k] = 0.f; }
#pragma unroll
  for (int u = 0; u < 5; u++) { cA[u] = 0.f; cB[u] = 0.f; }

  float xc[20], xn[20];   // FIRST uses only [0..4]
  if (FIRST) {
    const float* xp = xg + (size_t)n * 5;
#pragma unroll
    for (int c = 0; c < 5; c++) xc[c] = xp[c];
  } else {
    const float* xp = seq + (size_t)n * 20;
#pragma unroll
    for (int q = 0; q < 5; q++) {
      float4 v = *reinterpret_cast<const float4*>(xp + 4 * q);
      xc[4 * q] = v.x; xc[4 * q + 1] = v.y; xc[4 * q + 2] = v.z; xc[4 * q + 3] = v.w;
    }
  }

  for (int t = 0; t < T_; t++) {
    if (t + 1 < T_) {   // prefetch next timestep's input
      if (FIRST) {
        const float* xp = xg + ((size_t)(t + 1) * N_ + n) * 5;
#pragma unroll
        for (int c = 0; c < 5; c++) xn[c] = xp[c];
      } else {
        const float* xp = seq + ((size_t)(t + 1) * N_ + n) * 20;
#pragma unroll
        for (int q = 0; q < 5; q++) {
          float4 v = *reinterpret_cast<const float4*>(xp + 4 * q);
          xn[4 * q] = v.x; xn[4 * q + 1] = v.y; xn[4 * q + 2] = v.z; xn[4 * q + 3] = v.w;
        }
      }
    }
    float xin[20];
    if (FIRST) {   // embed + relu (natural order)
#pragma unroll
      for (int k = 0; k < 20; k++) {
        float a = xc[0] * embl[k] + xc[1] * embl[20 + k] + xc[2] * embl[40 + k]
                + xc[3] * embl[60 + k] + xc[4] * embl[80 + k];
        xin[k] = fmaxf(a, 0.f);
      }
    } else {
#pragma unroll
      for (int k = 0; k < 20; k++) xin[k] = xc[k];
    }
    lstm_layer_step(wts, biasl, baseA, bbA, xin, hA, cA);
    lstm_layer_step(wts, biasl, baseB, bbB, hA, hB, cB);

    if (r == 0) {   // part order == natural order at r==0
      float* op = seq + ((size_t)t * N_ + n) * 20;
      float4 v0 = {hB[0], hB[1], hB[2], hB[3]};
      float4 v1 = {hB[4], hB[5], hB[6], hB[7]};
      float4 v2 = {hB[8], hB[9], hB[10], hB[11]};
      float4 v3 = {hB[12], hB[13], hB[14], hB[15]};
      float4 v4 = {hB[16], hB[17], hB[18], hB[19]};
      float4* o4 = reinterpret_cast<float4*>(op);
      o4[0] = v0; o4[1] = v1; o4[2] = v2; o4[3] = v3; o4[4] = v4;
    }
#pragma unroll
    for (int k = 0; k < 20; k++) xc[k] = xn[k];
  }
}

// ---------------- attention over T, one wave per element ----------------
__global__ void __launch_bounds__(256) attn_kernel(
    const float* __restrict__ seq, const float* __restrict__ w1,
    const float* __restrict__ b1v, const float* __restrict__ w2,
    const float* __restrict__ b2v, float* __restrict__ xh, float* __restrict__ xhn) {
  const int wv = threadIdx.x >> 6;
  const int t = threadIdx.x & 63;
  const int n = (blockIdx.x << 2) + wv;
  const bool act = (t < T_);
  float enc[20];
#pragma unroll
  for (int k = 0; k < 20; k++) enc[k] = 0.0f;
  if (act) {
    const float* p = seq + (t * N_ + n) * H_;
#pragma unroll
    for (int q = 0; q < 5; q++) {
      float4 v = *reinterpret_cast<const float4*>(p + 4 * q);
      enc[4 * q] = v.x; enc[4 * q + 1] = v.y; enc[4 * q + 2] = v.z; enc[4 * q + 3] = v.w;
    }
  }
  float e = -3.0e38f;
  if (act) {
    e = b2v[0];
#pragma unroll 4
    for (int k = 0; k < 64; k++) {
      float s = b1v[k];
      const float* wr = w1 + k * 20;
#pragma unroll
      for (int m = 0; m < 20; m++) s += wr[m] * enc[m];
      s = fmaxf(s, 0.0f);
      e += w2[k] * s;
    }
  }
  float mx = e;
#pragma unroll
  for (int d = 32; d; d >>= 1) mx = fmaxf(mx, __shfl_xor(mx, d, 64));
  float p_ = act ? __expf(e - mx) : 0.0f;
  float sm = p_;
#pragma unroll
  for (int d = 32; d; d >>= 1) sm += __shfl_xor(sm, d, 64);
  float w = __fdividef(p_, sm);
  float a[20];
#pragma unroll
  for (int k = 0; k < 20; k++) a[k] = enc[k] * w;
#pragma unroll
  for (int d = 1; d < 64; d <<= 1) {
#pragma unroll
    for (int k = 0; k < 20; k++) a[k] += __shfl_xor(a[k], d, 64);
  }
  if (t == 0) {
    float* op = xh + n * 20;
    float s2 = 0.0f;
#pragma unroll
    for (int k = 0; k < 20; k++) s2 += a[k] * a[k];
#pragma unroll
    for (int q = 0; q < 5; q++) {
      float4 v; v.x = a[4 * q]; v.y = a[4 * q + 1]; v.z = a[4 * q + 2]; v.w = a[4 * q + 3];
      *reinterpret_cast<float4*>(op + 4 * q) = v;
    }
    xhn[n] = sqrtf(s2);
  }
}

// ---------------- x0 norms ----------------
__global__ void __launch_bounds__(256) x0norm_kernel(const float* __restrict__ x0,
                                                     float* __restrict__ nx0,
                                                     float* __restrict__ rx0) {
  int j = blockIdx.x * 256 + threadIdx.x;
  if (j >= N0_) return;
  float s = 0.f;
#pragma unroll
  for (int k = 0; k < 20; k++) { float v = x0[j * 20 + k]; s += v * v; }
  float nv = sqrtf(s);
  nx0[j] = nv;
  rx0[j] = 1.0f / nv;
}

// ---------------- top-6 cosine, 4 lanes per row ----------------
__device__ __forceinline__ bool better_(float v1, int i1, float v2, int i2) {
  return (v1 > v2) || (v1 == v2 && i1 < i2);
}

__device__ __forceinline__ void merge6(float tv[6], int ti[6], int d) {
  float cv[12]; int ci[12];
#pragma unroll
  for (int z = 0; z < 6; z++) { cv[z] = tv[z]; ci[z] = ti[z]; }
#pragma unroll
  for (int z = 0; z < 6; z++) {
    cv[6 + z] = __shfl_xor(tv[z], d, 64);
    ci[6 + z] = __shfl_xor(ti[z], d, 64);
  }
#pragma unroll
  for (int o = 0; o < 6; o++) {
    float bv = -3.0e38f; int bi = 0x7fffffff; int bm = -1;
#pragma unroll
    for (int m = 0; m < 12; m++) {
      bool bt = better_(cv[m], ci[m], bv, bi);
      if (bt) { bv = cv[m]; bi = ci[m]; bm = m; }
    }
    tv[o] = bv; ti[o] = bi;
#pragma unroll
    for (int m = 0; m < 12; m++) if (m == bm) cv[m] = -3.0e38f;
  }
}

__global__ void __launch_bounds__(256) topk_kernel(
    const float* __restrict__ x0, const float* __restrict__ xh,
    const float* __restrict__ xhn, const float* __restrict__ nx0,
    const float* __restrict__ rx0, int* __restrict__ top5) {
  const int gt = blockIdx.x * 256 + threadIdx.x;
  const int i = gt >> 2, sub = gt & 3;
  float q[20];
  const float* qp = xh + i * 20;
#pragma unroll
  for (int z = 0; z < 5; z++) {
    float4 v = *reinterpret_cast<const float4*>(qp + 4 * z);
    q[4 * z] = v.x; q[4 * z + 1] = v.y; q[4 * z + 2] = v.z; q[4 * z + 3] = v.w;
  }
  float tv[6]; int ti[6];
#pragma unroll
  for (int z = 0; z < 6; z++) { tv[z] = -1.0e30f; ti[z] = 0x7fffffff; }
  for (int j = sub; j < N0_; j += 4) {
    const float* xr = x0 + j * 20;
    float d0 = 0.f;
#pragma unroll
    for (int k = 0; k < 20; k++) d0 += q[k] * xr[k];
    float key = d0 * rx0[j];
    if (key > tv[5]) {       // within-lane j ascending => strict > keeps stability
      tv[5] = key; ti[5] = j;
#pragma unroll
      for (int z = 5; z >= 1; z--) {
        bool sw = better_(tv[z], ti[z], tv[z - 1], ti[z - 1]);
        if (sw) {
          float fv = tv[z]; tv[z] = tv[z - 1]; tv[z - 1] = fv;
          int iv = ti[z]; ti[z] = ti[z - 1]; ti[z - 1] = iv;
        }
      }
    }
  }
  merge6(tv, ti, 1);
  merge6(tv, ti, 2);
  if (sub == 0) {
    const float* xr = x0 + ti[0] * 20;
    float d0 = 0.f;
#pragma unroll
    for (int k = 0; k < 20; k++) d0 += q[k] * xr[k];
    float a = (d0 / xhn[i]) / nx0[ti[0]];   // replicate ref's exact-match branch
    int base = (a == 1.0f) ? 1 : 0;
#pragma unroll
    for (int z = 0; z < 5; z++) top5[i * 5 + z] = ti[base + z];
  }
}

// ---------------- SAGE layer-1 aggregation over edge_0 ----------------
__global__ void __launch_bounds__(256) scatter_kernel(const int* __restrict__ edge,
                                                      const float* __restrict__ x0,
                                                      float* sum1, float* cnt1) {
  int e = blockIdx.x * 256 + threadIdx.x;
  if (e >= E0_) return;
  int s = edge[e], d = edge[E0_ + e];
  const float* xr = x0 + s * 20;
  float* dr = sum1 + d * 20;
#pragma unroll
  for (int k = 0; k < 20; k++) atomicAdd(dr + k, xr[k]);
  atomicAdd(cnt1 + d, 1.0f);
}

__global__ void __launch_bounds__(256) base_kernel(
    const float* __restrict__ x0, const float* __restrict__ sum1,
    const float* __restrict__ cnt1, const float* __restrict__ w1l,
    const float* __restrict__ w1r, const float* __restrict__ b1,
    float* __restrict__ obase) {
  int j = blockIdx.x * 256 + threadIdx.x;
  if (j >= N0_) return;
  float cm = fmaxf(cnt1[j], 1.0f);
  float mean[20], xv[20];
#pragma unroll
  for (int k = 0; k < 20; k++) {
    mean[k] = sum1[j * 20 + k] / cm;
    xv[k] = x0[j * 20 + k];
  }
#pragma unroll
  for (int c = 0; c < HC_; c++) {
    float a = b1[c];
#pragma unroll
    for (int k = 0; k < 20; k++) a += mean[k] * w1l[c * 20 + k];
#pragma unroll
    for (int k = 0; k < 20; k++) a += xv[k] * w1r[c * 20 + k];
    obase[j * HC_ + c] = fmaxf(a, 0.0f);
  }
}

// ---------------- SAGE layer-2 at new nodes + linear + softmax ----------------
__global__ void __launch_bounds__(256) final_kernel(
    const float* __restrict__ xh, const int* __restrict__ top5,
    const float* __restrict__ obase, const float* __restrict__ w1r,
    const float* __restrict__ b1, const float* __restrict__ w2l,
    const float* __restrict__ w2r, const float* __restrict__ b2,
    const float* __restrict__ wlin, const float* __restrict__ blin,
    float* __restrict__ out) {
  int n = blockIdx.x * 256 + threadIdx.x;
  if (n >= N_) return;
  float xq[20];
#pragma unroll
  for (int k = 0; k < 20; k++) xq[k] = xh[n * 20 + k];
  float onw[15];   // layer-1 output at this new node (mean = 0: no incoming edge_0)
#pragma unroll
  for (int c = 0; c < HC_; c++) {
    float a = b1[c];
#pragma unroll
    for (int k = 0; k < 20; k++) a += xq[k] * w1r[c * 20 + k];
    onw[c] = fmaxf(a, 0.0f);
  }
  float mean[15];
#pragma unroll
  for (int c = 0; c < HC_; c++) mean[c] = 0.0f;
#pragma unroll
  for (int z = 0; z < K_; z++) {
    int idx = top5[n * 5 + z];
#pragma unroll
    for (int c = 0; c < HC_; c++) mean[c] += obase[idx * HC_ + c];
  }
#pragma unroll
  for (int c = 0; c < HC_; c++) mean[c] = mean[c] / 5.0f;
  float lg[3];
#pragma unroll
  for (int cl = 0; cl < 3; cl++) lg[cl] = blin[cl];
#pragma unroll
  for (int dd = 0; dd < 20; dd++) {
    float v = b2[dd];
#pragma unroll
    for (int c = 0; c < HC_; c++) v += mean[c] * w2l[dd * HC_ + c] + onw[c] * w2r[dd * HC_ + c];
#pragma unroll
    for (int cl = 0; cl < 3; cl++) lg[cl] += v * wlin[cl * 20 + dd];
  }
  float m = fmaxf(lg[0], fmaxf(lg[1], lg[2]));
  float e0 = expf(lg[0] - m), e1 = expf(lg[1] - m), e2 = expf(lg[2] - m);
  float s = e0 + e1 + e2;
  out[n * 3 + 0] = e0 / s;
  out[n * 3 + 1] = e1 / s;
  out[n * 3 + 2] = e2 / s;
}

extern "C" void kernel_launch(void* const* d_in, const int* in_sizes, int n_in,
                              void* d_out, int out_size, void* d_ws, size_t ws_size,
                              hipStream_t stream) {
  const float* x    = (const float*)d_in[0];
  const float* x0   = (const float*)d_in[1];
  const float* embw = (const float*)d_in[2];
  const float* Wih  = (const float*)d_in[3];
  const float* Whh  = (const float*)d_in[4];
  const float* bih  = (const float*)d_in[5];
  const float* bhh  = (const float*)d_in[6];
  const float* aw1  = (const float*)d_in[7];
  const float* ab1  = (const float*)d_in[8];
  const float* aw2  = (const float*)d_in[9];
  const float* ab2  = (const float*)d_in[10];
  const float* w1l  = (const float*)d_in[11];
  const float* w1r  = (const float*)d_in[12];
  const float* b1   = (const float*)d_in[13];
  const float* w2l  = (const float*)d_in[14];
  const float* w2r  = (const float*)d_in[15];
  const float* b2   = (const float*)d_in[16];
  const float* wlin = (const float*)d_in[17];
  const float* blin = (const float*)d_in[18];
  const int* edge0  = (const int*)d_in[19];

  float* ws    = (float*)d_ws;
  float* seq   = ws + OFF_SEQ;
  float* xh    = ws + OFF_XH;
  float* xhn   = ws + OFF_XHN;
  float* nx0   = ws + OFF_NX0;
  float* rx0   = ws + OFF_RX0;
  int*   top5  = (int*)(ws + OFF_TOP5);
  float* sum1  = ws + OFF_SUM1;
  float* cnt1  = ws + OFF_CNT1;
  float* obase = ws + OFF_OBASE;
  float* out   = (float*)d_out;

  hipMemsetAsync(sum1, 0, (size_t)(N0_ * H_ + N0_) * sizeof(float), stream);
  lstm2_kernel<true><<<N_ / 64, 256, 0, stream>>>(x, embw, Wih, Whh, bih, bhh, seq);
  lstm2_kernel<false><<<N_ / 64, 256, 0, stream>>>(x, embw, Wih + 2 * 1600, Whh + 2 * 1600,
                                                   bih + 2 * 80, bhh + 2 * 80, seq);
  attn_kernel<<<N_ / 4, 256, 0, stream>>>(seq, aw1, ab1, aw2, ab2, xh, xhn);
  x0norm_kernel<<<(N0_ + 255) / 256, 256, 0, stream>>>(x0, nx0, rx0);
  topk_kernel<<<(N_ * 4) / 256, 256, 0, stream>>>(x0, xh, xhn, nx0, rx0, top5);
  scatter_kernel<<<(E0_ + 255) / 256, 256, 0, stream>>>(edge0, x0, sum1, cnt1);
  base_kernel<<<(N0_ + 255) / 256, 256, 0, stream>>>(x0, sum1, cnt1, w1l, w1r, b1, obase);
  final_kernel<<<N_ / 256, 256, 0, stream>>>(xh, top5, obase, w1r, b1, w2l, w2r, b2,
                                             wlin, blin, out);
}

// Round 4
// 2164.750 us; speedup vs baseline: 1.4739x; 1.4739x over previous
//
#include <hip/hip_runtime.h>
#include <math.h>

#define T_ 60
#define N_ 16384
#define C_ 5
#define H_ 20
#define G_ 80
#define HC_ 15
#define N0_ 3190
#define E0_ 31900
#define K_ 5

// workspace layout (float offsets)
#define OFF_SEQ   0
#define OFF_XH    (T_*N_*H_)            // 19,660,800
#define OFF_XHN   (OFF_XH + N_*H_)
#define OFF_NX0   (OFF_XHN + N_)
#define OFF_RX0   (OFF_NX0 + N0_)
#define OFF_TOP5  (OFF_RX0 + N0_)       // int[ N_*K_ ]
#define OFF_SUM1  (OFF_TOP5 + N_*K_)
#define OFF_CNT1  (OFF_SUM1 + N0_*H_)
#define OFF_OBASE (OFF_CNT1 + N0_)

__device__ __forceinline__ float sigf(float x) {
  return __fdividef(1.0f, 1.0f + __expf(-x));
}
__device__ __forceinline__ float tanhf_fast(float x) {
  float xc = fminf(fmaxf(x, -44.0f), 44.0f);
  float e = __expf(2.0f * xc);
  return __fdividef(e - 1.0f, e + 1.0f);
}

// ============================================================================
// LSTM layer kernel "ks8": one layer per dispatch (4-layer & 2-layer fusion
// both spilled: VGPR=256 + >1GB scratch fetch, rounds 2-3).
// Decomposition: 8 thread-slots per element-PAIR. lane bits: role=bits0-1,
// slot_b0=bit2, kh=bit3, slot_b1..2=bits4-5. Each thread serves 2 elements
// (slot, slot+8), one role (units 5r..5r+4, all 4 gates = 20 rows), one
// k-half: kh=0 -> Wih*x part (+bias), kh=1 -> Whh*h part.
//  - weight quad feeds 8 fmacs (2 el * 4 k) => LDS stream halved vs round-1.
//  - gate combine: acc += shfl_xor(acc, 8)   (row_half_mirror DPP, no LDS)
//  - h exchange:  shfl_xor 1/2/3 (quad_perm DPP), h kept in part order
//    H[5d+u] = h_nat[5*(r^d)+u]; Whh columns pre-permuted at stage time
//    (round-2-verified formula). Barrier-free t-loop, no hx LDS.
//  - weight blocks stride WSTR=420 words; 420%32=4 => the 8 (r,kh) blocks
//    start at banks 0,4,..,28: a wave's 8-address b128 multicast covers all
//    32 banks exactly once -> conflict-free.
// ============================================================================

#define WSTR 420

template <bool FIRST>
__global__ void __launch_bounds__(256, 1) lstm_ks8_kernel(
    const float* __restrict__ xg,      // [T, N, 5] raw codes (FIRST only)
    const float* __restrict__ embw,    // [5, 20]              (FIRST only)
    const float* __restrict__ Wih,     // [80, 20] this layer
    const float* __restrict__ Whh,     // [80, 20]
    const float* __restrict__ bih,     // [80]
    const float* __restrict__ bhh,     // [80]
    float* __restrict__ seq) {         // in (!FIRST) and out: [T, N, 20]
  __shared__ __align__(16) float wts[8 * WSTR];
  __shared__ float biasl[8 * 20];
  __shared__ float embl[100];
  const int tid = threadIdx.x;

  for (int idx = tid; idx < 8 * 400; idx += 256) {
    int blk = idx / 400, e = idx % 400;
    int r = blk >> 1, kh = blk & 1;
    int lr = e / 20, k = e % 20;
    int g = lr / 5, u = lr % 5;
    int grow = g * 20 + 5 * r + u;
    float v;
    if (kh == 0) {
      v = Wih[grow * 20 + k];                      // input arrives natural
    } else {
      int kk = 5 * (r ^ (k / 5)) + (k % 5);        // part-order h operand
      v = Whh[grow * 20 + kk];
    }
    wts[blk * WSTR + lr * 20 + k] = v;
  }
  if (tid < 160) {
    int blk = tid / 20, lr = tid % 20;
    int r = blk >> 1, kh = blk & 1;
    int g = lr / 5, u = lr % 5;
    int grow = g * 20 + 5 * r + u;
    biasl[blk * 20 + lr] = kh ? 0.0f : (bih[grow] + bhh[grow]);
  }
  if (FIRST && tid < 100) embl[tid] = embw[tid];
  __syncthreads();

  const int lane = tid & 63;
  const int wv = tid >> 6;
  const int r = lane & 3;
  const int kh = (lane >> 3) & 1;
  const int slot = ((lane >> 2) & 1) | ((lane >> 3) & 6);   // bits 2,4,5
  const int n0 = (blockIdx.x << 6) + (wv << 4) + slot;      // elements n0, n0+8
  const int wb = ((r << 1) | kh) * WSTR;
  const float* bl = &biasl[((r << 1) | kh) * 20];

  float op[2][20];   // kh=0: x_t (natural); kh=1: H part-order
  float cc[2][5];
#pragma unroll
  for (int e = 0; e < 2; e++) {
#pragma unroll
    for (int k = 0; k < 20; k++) op[e][k] = 0.0f;
#pragma unroll
    for (int u = 0; u < 5; u++) cc[e][u] = 0.0f;
  }

  float xc[2][5], xn[2][5];   // FIRST raw codes
  float opn[2][20];           // !FIRST prefetched next input
  if (kh == 0) {
#pragma unroll
    for (int e = 0; e < 2; e++) {
      int n = n0 + e * 8;
      if (FIRST) {
        const float* xp = xg + (size_t)n * 5;
#pragma unroll
        for (int c = 0; c < 5; c++) xc[e][c] = xp[c];
      } else {
        const float* xp = seq + (size_t)n * 20;
#pragma unroll
        for (int q = 0; q < 5; q++) {
          float4 v = *reinterpret_cast<const float4*>(xp + 4 * q);
          op[e][4 * q] = v.x; op[e][4 * q + 1] = v.y;
          op[e][4 * q + 2] = v.z; op[e][4 * q + 3] = v.w;
        }
      }
    }
  }

  for (int t = 0; t < T_; t++) {
    if (kh == 0 && t + 1 < T_) {   // prefetch next-step input
#pragma unroll
      for (int e = 0; e < 2; e++) {
        int n = n0 + e * 8;
        if (FIRST) {
          const float* xp = xg + ((size_t)(t + 1) * N_ + n) * 5;
#pragma unroll
          for (int c = 0; c < 5; c++) xn[e][c] = xp[c];
        } else {
          const float* xp = seq + ((size_t)(t + 1) * N_ + n) * 20;
#pragma unroll
          for (int q = 0; q < 5; q++) {
            float4 v = *reinterpret_cast<const float4*>(xp + 4 * q);
            opn[e][4 * q] = v.x; opn[e][4 * q + 1] = v.y;
            opn[e][4 * q + 2] = v.z; opn[e][4 * q + 3] = v.w;
          }
        }
      }
    }
    if (FIRST && kh == 0) {   // embed + relu into op (natural order)
#pragma unroll
      for (int e = 0; e < 2; e++)
#pragma unroll
        for (int k = 0; k < 20; k++) {
          float a = xc[e][0] * embl[k] + xc[e][1] * embl[20 + k]
                  + xc[e][2] * embl[40 + k] + xc[e][3] * embl[60 + k]
                  + xc[e][4] * embl[80 + k];
          op[e][k] = fmaxf(a, 0.f);
        }
    }
    // partial pre-activations: 20 rows x 20 cols x 2 elements
    float acc[2][20];
#pragma unroll
    for (int lr = 0; lr < 20; lr++) {
      float a0 = bl[lr], a1 = bl[lr];
      const float* wr = &wts[wb + lr * 20];
#pragma unroll
      for (int k = 0; k < 20; k++) {
        float w = wr[k];
        a0 += w * op[0][k];
        a1 += w * op[1][k];
      }
      acc[0][lr] = a0; acc[1][lr] = a1;
    }
    // combine k-halves (xor8) + gates (computed redundantly by both kh)
    float hn[2][5];
#pragma unroll
    for (int e = 0; e < 2; e++)
#pragma unroll
      for (int u = 0; u < 5; u++) {
        float ai = acc[e][u]      + __shfl_xor(acc[e][u], 8, 64);
        float af = acc[e][5 + u]  + __shfl_xor(acc[e][5 + u], 8, 64);
        float ag = acc[e][10 + u] + __shfl_xor(acc[e][10 + u], 8, 64);
        float ao = acc[e][15 + u] + __shfl_xor(acc[e][15 + u], 8, 64);
        float cu = sigf(af) * cc[e][u] + sigf(ai) * tanhf_fast(ag);
        cc[e][u] = cu;
        hn[e][u] = sigf(ao) * tanhf_fast(cu);
      }
    // h-exchange across roles (quad_perm DPP); kh=1 keeps part-order H as
    // next-step operand; (r==0,kh==0) builds natural h in op for the store
    // (safe to clobber: kh=0 op is regenerated/overwritten each step).
#pragma unroll
    for (int e = 0; e < 2; e++)
#pragma unroll
      for (int u = 0; u < 5; u++) {
        float h0 = hn[e][u];
        float h1 = __shfl_xor(h0, 1, 64);
        float h2 = __shfl_xor(h0, 2, 64);
        float h3 = __shfl_xor(h0, 3, 64);
        if (kh == 1 || r == 0) {
          op[e][u] = h0; op[e][5 + u] = h1; op[e][10 + u] = h2; op[e][15 + u] = h3;
        }
      }
    if (r == 0 && kh == 0) {
#pragma unroll
      for (int e = 0; e < 2; e++) {
        float* o = seq + ((size_t)t * N_ + (n0 + e * 8)) * 20;
        float4* o4 = reinterpret_cast<float4*>(o);
#pragma unroll
        for (int q = 0; q < 5; q++) {
          float4 v; v.x = op[e][4 * q]; v.y = op[e][4 * q + 1];
          v.z = op[e][4 * q + 2]; v.w = op[e][4 * q + 3];
          o4[q] = v;
        }
      }
    }
    if (kh == 0 && t + 1 < T_) {
      if (FIRST) {
#pragma unroll
        for (int e = 0; e < 2; e++)
#pragma unroll
          for (int c = 0; c < 5; c++) xc[e][c] = xn[e][c];
      } else {
#pragma unroll
        for (int e = 0; e < 2; e++)
#pragma unroll
          for (int k = 0; k < 20; k++) op[e][k] = opn[e][k];
      }
    }
  }
}

// ---------------- attention over T, one wave per element ----------------
__global__ void __launch_bounds__(256) attn_kernel(
    const float* __restrict__ seq, const float* __restrict__ w1,
    const float* __restrict__ b1v, const float* __restrict__ w2,
    const float* __restrict__ b2v, float* __restrict__ xh, float* __restrict__ xhn) {
  const int wv = threadIdx.x >> 6;
  const int t = threadIdx.x & 63;
  const int n = (blockIdx.x << 2) + wv;
  const bool act = (t < T_);
  float enc[20];
#pragma unroll
  for (int k = 0; k < 20; k++) enc[k] = 0.0f;
  if (act) {
    const float* p = seq + (t * N_ + n) * H_;
#pragma unroll
    for (int q = 0; q < 5; q++) {
      float4 v = *reinterpret_cast<const float4*>(p + 4 * q);
      enc[4 * q] = v.x; enc[4 * q + 1] = v.y; enc[4 * q + 2] = v.z; enc[4 * q + 3] = v.w;
    }
  }
  float e = -3.0e38f;
  if (act) {
    e = b2v[0];
#pragma unroll 4
    for (int k = 0; k < 64; k++) {
      float s = b1v[k];
      const float* wr = w1 + k * 20;
#pragma unroll
      for (int m = 0; m < 20; m++) s += wr[m] * enc[m];
      s = fmaxf(s, 0.0f);
      e += w2[k] * s;
    }
  }
  float mx = e;
#pragma unroll
  for (int d = 32; d; d >>= 1) mx = fmaxf(mx, __shfl_xor(mx, d, 64));
  float p_ = act ? __expf(e - mx) : 0.0f;
  float sm = p_;
#pragma unroll
  for (int d = 32; d; d >>= 1) sm += __shfl_xor(sm, d, 64);
  float w = __fdividef(p_, sm);
  float a[20];
#pragma unroll
  for (int k = 0; k < 20; k++) a[k] = enc[k] * w;
#pragma unroll
  for (int d = 1; d < 64; d <<= 1) {
#pragma unroll
    for (int k = 0; k < 20; k++) a[k] += __shfl_xor(a[k], d, 64);
  }
  if (t == 0) {
    float* op = xh + n * 20;
    float s2 = 0.0f;
#pragma unroll
    for (int k = 0; k < 20; k++) s2 += a[k] * a[k];
#pragma unroll
    for (int q = 0; q < 5; q++) {
      float4 v; v.x = a[4 * q]; v.y = a[4 * q + 1]; v.z = a[4 * q + 2]; v.w = a[4 * q + 3];
      *reinterpret_cast<float4*>(op + 4 * q) = v;
    }
    xhn[n] = sqrtf(s2);
  }
}

// ---------------- x0 norms ----------------
__global__ void __launch_bounds__(256) x0norm_kernel(const float* __restrict__ x0,
                                                     float* __restrict__ nx0,
                                                     float* __restrict__ rx0) {
  int j = blockIdx.x * 256 + threadIdx.x;
  if (j >= N0_) return;
  float s = 0.f;
#pragma unroll
  for (int k = 0; k < 20; k++) { float v = x0[j * 20 + k]; s += v * v; }
  float nv = sqrtf(s);
  nx0[j] = nv;
  rx0[j] = 1.0f / nv;
}

// ---------------- top-6 cosine, 4 lanes per row ----------------
__device__ __forceinline__ bool better_(float v1, int i1, float v2, int i2) {
  return (v1 > v2) || (v1 == v2 && i1 < i2);
}

__device__ __forceinline__ void merge6(float tv[6], int ti[6], int d) {
  float cv[12]; int ci[12];
#pragma unroll
  for (int z = 0; z < 6; z++) { cv[z] = tv[z]; ci[z] = ti[z]; }
#pragma unroll
  for (int z = 0; z < 6; z++) {
    cv[6 + z] = __shfl_xor(tv[z], d, 64);
    ci[6 + z] = __shfl_xor(ti[z], d, 64);
  }
#pragma unroll
  for (int o = 0; o < 6; o++) {
    float bv = -3.0e38f; int bi = 0x7fffffff; int bm = -1;
#pragma unroll
    for (int m = 0; m < 12; m++) {
      bool bt = better_(cv[m], ci[m], bv, bi);
      if (bt) { bv = cv[m]; bi = ci[m]; bm = m; }
    }
    tv[o] = bv; ti[o] = bi;
#pragma unroll
    for (int m = 0; m < 12; m++) if (m == bm) cv[m] = -3.0e38f;
  }
}

__global__ void __launch_bounds__(256) topk_kernel(
    const float* __restrict__ x0, const float* __restrict__ xh,
    const float* __restrict__ xhn, const float* __restrict__ nx0,
    const float* __restrict__ rx0, int* __restrict__ top5) {
  const int gt = blockIdx.x * 256 + threadIdx.x;
  const int i = gt >> 2, sub = gt & 3;
  float q[20];
  const float* qp = xh + i * 20;
#pragma unroll
  for (int z = 0; z < 5; z++) {
    float4 v = *reinterpret_cast<const float4*>(qp + 4 * z);
    q[4 * z] = v.x; q[4 * z + 1] = v.y; q[4 * z + 2] = v.z; q[4 * z + 3] = v.w;
  }
  float tv[6]; int ti[6];
#pragma unroll
  for (int z = 0; z < 6; z++) { tv[z] = -1.0e30f; ti[z] = 0x7fffffff; }
  for (int j = sub; j < N0_; j += 4) {
    const float* xr = x0 + j * 20;
    float d0 = 0.f;
#pragma unroll
    for (int k = 0; k < 20; k++) d0 += q[k] * xr[k];
    float key = d0 * rx0[j];
    if (key > tv[5]) {       // within-lane j ascending => strict > keeps stability
      tv[5] = key; ti[5] = j;
#pragma unroll
      for (int z = 5; z >= 1; z--) {
        bool sw = better_(tv[z], ti[z], tv[z - 1], ti[z - 1]);
        if (sw) {
          float fv = tv[z]; tv[z] = tv[z - 1]; tv[z - 1] = fv;
          int iv = ti[z]; ti[z] = ti[z - 1]; ti[z - 1] = iv;
        }
      }
    }
  }
  merge6(tv, ti, 1);
  merge6(tv, ti, 2);
  if (sub == 0) {
    const float* xr = x0 + ti[0] * 20;
    float d0 = 0.f;
#pragma unroll
    for (int k = 0; k < 20; k++) d0 += q[k] * xr[k];
    float a = (d0 / xhn[i]) / nx0[ti[0]];   // replicate ref's exact-match branch
    int base = (a == 1.0f) ? 1 : 0;
#pragma unroll
    for (int z = 0; z < 5; z++) top5[i * 5 + z] = ti[base + z];
  }
}

// ---------------- SAGE layer-1 aggregation over edge_0 ----------------
__global__ void __launch_bounds__(256) scatter_kernel(const int* __restrict__ edge,
                                                      const float* __restrict__ x0,
                                                      float* sum1, float* cnt1) {
  int e = blockIdx.x * 256 + threadIdx.x;
  if (e >= E0_) return;
  int s = edge[e], d = edge[E0_ + e];
  const float* xr = x0 + s * 20;
  float* dr = sum1 + d * 20;
#pragma unroll
  for (int k = 0; k < 20; k++) atomicAdd(dr + k, xr[k]);
  atomicAdd(cnt1 + d, 1.0f);
}

__global__ void __launch_bounds__(256) base_kernel(
    const float* __restrict__ x0, const float* __restrict__ sum1,
    const float* __restrict__ cnt1, const float* __restrict__ w1l,
    const float* __restrict__ w1r, const float* __restrict__ b1,
    float* __restrict__ obase) {
  int j = blockIdx.x * 256 + threadIdx.x;
  if (j >= N0_) return;
  float cm = fmaxf(cnt1[j], 1.0f);
  float mean[20], xv[20];
#pragma unroll
  for (int k = 0; k < 20; k++) {
    mean[k] = sum1[j * 20 + k] / cm;
    xv[k] = x0[j * 20 + k];
  }
#pragma unroll
  for (int c = 0; c < HC_; c++) {
    float a = b1[c];
#pragma unroll
    for (int k = 0; k < 20; k++) a += mean[k] * w1l[c * 20 + k];
#pragma unroll
    for (int k = 0; k < 20; k++) a += xv[k] * w1r[c * 20 + k];
    obase[j * HC_ + c] = fmaxf(a, 0.0f);
  }
}

// ---------------- SAGE layer-2 at new nodes + linear + softmax ----------------
__global__ void __launch_bounds__(256) final_kernel(
    const float* __restrict__ xh, const int* __restrict__ top5,
    const float* __restrict__ obase, const float* __restrict__ w1r,
    const float* __restrict__ b1, const float* __restrict__ w2l,
    const float* __restrict__ w2r, const float* __restrict__ b2,
    const float* __restrict__ wlin, const float* __restrict__ blin,
    float* __restrict__ out) {
  int n = blockIdx.x * 256 + threadIdx.x;
  if (n >= N_) return;
  float xq[20];
#pragma unroll
  for (int k = 0; k < 20; k++) xq[k] = xh[n * 20 + k];
  float onw[15];   // layer-1 output at this new node (mean = 0: no incoming edge_0)
#pragma unroll
  for (int c = 0; c < HC_; c++) {
    float a = b1[c];
#pragma unroll
    for (int k = 0; k < 20; k++) a += xq[k] * w1r[c * 20 + k];
    onw[c] = fmaxf(a, 0.0f);
  }
  float mean[15];
#pragma unroll
  for (int c = 0; c < HC_; c++) mean[c] = 0.0f;
#pragma unroll
  for (int z = 0; z < K_; z++) {
    int idx = top5[n * 5 + z];
#pragma unroll
    for (int c = 0; c < HC_; c++) mean[c] += obase[idx * HC_ + c];
  }
#pragma unroll
  for (int c = 0; c < HC_; c++) mean[c] = mean[c] / 5.0f;
  float lg[3];
#pragma unroll
  for (int cl = 0; cl < 3; cl++) lg[cl] = blin[cl];
#pragma unroll
  for (int dd = 0; dd < 20; dd++) {
    float v = b2[dd];
#pragma unroll
    for (int c = 0; c < HC_; c++) v += mean[c] * w2l[dd * HC_ + c] + onw[c] * w2r[dd * HC_ + c];
#pragma unroll
    for (int cl = 0; cl < 3; cl++) lg[cl] += v * wlin[cl * 20 + dd];
  }
  float m = fmaxf(lg[0], fmaxf(lg[1], lg[2]));
  float e0 = expf(lg[0] - m), e1 = expf(lg[1] - m), e2 = expf(lg[2] - m);
  float s = e0 + e1 + e2;
  out[n * 3 + 0] = e0 / s;
  out[n * 3 + 1] = e1 / s;
  out[n * 3 + 2] = e2 / s;
}

extern "C" void kernel_launch(void* const* d_in, const int* in_sizes, int n_in,
                              void* d_out, int out_size, void* d_ws, size_t ws_size,
                              hipStream_t stream) {
  const float* x    = (const float*)d_in[0];
  const float* x0   = (const float*)d_in[1];
  const float* embw = (const float*)d_in[2];
  const float* Wih  = (const float*)d_in[3];
  const float* Whh  = (const float*)d_in[4];
  const float* bih  = (const float*)d_in[5];
  const float* bhh  = (const float*)d_in[6];
  const float* aw1  = (const float*)d_in[7];
  const float* ab1  = (const float*)d_in[8];
  const float* aw2  = (const float*)d_in[9];
  const float* ab2  = (const float*)d_in[10];
  const float* w1l  = (const float*)d_in[11];
  const float* w1r  = (const float*)d_in[12];
  const float* b1   = (const float*)d_in[13];
  const float* w2l  = (const float*)d_in[14];
  const float* w2r  = (const float*)d_in[15];
  const float* b2   = (const float*)d_in[16];
  const float* wlin = (const float*)d_in[17];
  const float* blin = (const float*)d_in[18];
  const int* edge0  = (const int*)d_in[19];

  float* ws    = (float*)d_ws;
  float* seq   = ws + OFF_SEQ;
  float* xh    = ws + OFF_XH;
  float* xhn   = ws + OFF_XHN;
  float* nx0   = ws + OFF_NX0;
  float* rx0   = ws + OFF_RX0;
  int*   top5  = (int*)(ws + OFF_TOP5);
  float* sum1  = ws + OFF_SUM1;
  float* cnt1  = ws + OFF_CNT1;
  float* obase = ws + OFF_OBASE;
  float* out   = (float*)d_out;

  hipMemsetAsync(sum1, 0, (size_t)(N0_ * H_ + N0_) * sizeof(float), stream);
  lstm_ks8_kernel<true><<<N_ / 64, 256, 0, stream>>>(x, embw, Wih, Whh, bih, bhh, seq);
  for (int l = 1; l < 4; l++)
    lstm_ks8_kernel<false><<<N_ / 64, 256, 0, stream>>>(x, embw, Wih + l * 1600,
                                                        Whh + l * 1600, bih + l * 80,
                                                        bhh + l * 80, seq);
  attn_kernel<<<N_ / 4, 256, 0, stream>>>(seq, aw1, ab1, aw2, ab2, xh, xhn);
  x0norm_kernel<<<(N0_ + 255) / 256, 256, 0, stream>>>(x0, nx0, rx0);
  topk_kernel<<<(N_ * 4) / 256, 256, 0, stream>>>(x0, xh, xhn, nx0, rx0, top5);
  scatter_kernel<<<(E0_ + 255) / 256, 256, 0, stream>>>(edge0, x0, sum1, cnt1);
  base_kernel<<<(N0_ + 255) / 256, 256, 0, stream>>>(x0, sum1, cnt1, w1l, w1r, b1, obase);
  final_kernel<<<N_ / 256, 256, 0, stream>>>(xh, top5, obase, w1r, b1, w2l, w2r, b2,
                                             wlin, blin, out);
}